// Round 3
// baseline (606.249 us; speedup 1.0000x reference)
//
#include <hip/hip_runtime.h>
#include <hip/hip_bf16.h>
#include <math.h>

#define N_NODES 100000
#define N_EDGES 1600000
#define F0 32
#define F1 16
#define F2 8
#define NCLS 6
#define NGRAPH 64
#define SCAN_THREADS 1024

// ---------------- CSR build: histogram of dst degrees ----------------
__global__ void hist_k(const int* __restrict__ ei, int* __restrict__ deg) {
    int e = blockIdx.x * blockDim.x + threadIdx.x;
    if (e >= N_EDGES) return;
    atomicAdd(&deg[ei[N_EDGES + e]], 1);
}

// ---- single-block exclusive scan of deg -> row_start (+cursor copy) ----
__global__ void scan_k(const int* __restrict__ deg,
                       int* __restrict__ row_start,
                       int* __restrict__ cursor) {
    __shared__ int part[SCAN_THREADS];
    int t = threadIdx.x;
    const int CHUNK = (N_NODES + SCAN_THREADS - 1) / SCAN_THREADS; // 98
    int lo = t * CHUNK;
    int hi = lo + CHUNK; if (hi > N_NODES) hi = N_NODES;
    int s = 0;
    for (int i = lo; i < hi; i++) s += deg[i];
    part[t] = s;
    __syncthreads();
    // Hillis-Steele inclusive scan over the 1024 partials
    for (int off = 1; off < SCAN_THREADS; off <<= 1) {
        int v = (t >= off) ? part[t - off] : 0;
        __syncthreads();
        part[t] += v;
        __syncthreads();
    }
    int base = (t == 0) ? 0 : part[t - 1];
    for (int i = lo; i < hi; i++) {
        int d = deg[i];
        row_start[i] = base;
        cursor[i] = base;
        base += d;
    }
}

// ---- fill: col[pos] = src, pos = fetch-add on cursor[dst] ----
__global__ void fill_k(const int* __restrict__ ei,
                       int* __restrict__ cursor,
                       int* __restrict__ col) {
    int e = blockIdx.x * blockDim.x + threadIdx.x;
    if (e >= N_EDGES) return;
    int src = ei[e];
    int dst = ei[N_EDGES + e];
    int pos = atomicAdd(&cursor[dst], 1);
    col[pos] = src;
}

// ---- xform1: xw1 = x @ W1a (32 -> 16, projected before aggregation) ----
__global__ void xform1_k(const float* __restrict__ x,
                         const float* __restrict__ W1a,
                         float* __restrict__ xw1) {
    __shared__ float sW[F0 * F1];
    int t = threadIdx.x;
    for (int i = t; i < F0 * F1; i += blockDim.x) sW[i] = W1a[i];
    __syncthreads();
    int n = blockIdx.x * blockDim.x + t;
    if (n >= N_NODES) return;
    float xi[F0];
#pragma unroll
    for (int k = 0; k < F0; k++) xi[k] = x[n * F0 + k];
#pragma unroll
    for (int j = 0; j < F1; j++) {
        float s = 0.0f;
#pragma unroll
        for (int k = 0; k < F0; k++) s += xi[k] * sW[k * F1 + j];
        xw1[n * F1 + j] = s;
    }
}

// ---- gather 16 feats: agg[n] = sum over in-edges of v[col[j]] ----
__global__ void gather16_k(const float* __restrict__ v,
                           const int* __restrict__ row_start,
                           const int* __restrict__ deg,
                           const int* __restrict__ col,
                           float* __restrict__ agg) {
    int tid = blockIdx.x * blockDim.x + threadIdx.x;
    int n = tid >> 4;
    int f = tid & 15;
    if (n >= N_NODES) return;
    int lo = row_start[n];
    int d = deg[n];
    float s = 0.0f;
    for (int j = 0; j < d; j++)
        s += v[col[lo + j] * F1 + f];
    agg[n * F1 + f] = s;
}

// ---- gather 8 feats ----
__global__ void gather8_k(const float* __restrict__ v,
                          const int* __restrict__ row_start,
                          const int* __restrict__ deg,
                          const int* __restrict__ col,
                          float* __restrict__ agg) {
    int tid = blockIdx.x * blockDim.x + threadIdx.x;
    int n = tid >> 3;
    int f = tid & 7;
    if (n >= N_NODES) return;
    int lo = row_start[n];
    int d = deg[n];
    float s = 0.0f;
    for (int j = 0; j < d; j++)
        s += v[col[lo + j] * F2 + f];
    agg[n * F2 + f] = s;
}

// ---- mlp1b: u = relu(xw1 + agg1w + b1a); h1 = relu(u@W1b + b1b);
//      h1w = h1 @ W2a (projected for the next gather) ----
__global__ void mlp1b_k(const float* __restrict__ xw1,
                        const float* __restrict__ agg1w,
                        const float* __restrict__ b1a,
                        const float* __restrict__ W1b, const float* __restrict__ b1b,
                        const float* __restrict__ W2a,
                        float* __restrict__ h1w) {
    __shared__ float sW1b[F1 * F1];
    __shared__ float sW2a[F1 * F2];
    __shared__ float sb1a[F1];
    __shared__ float sb1b[F1];
    int t = threadIdx.x;
    for (int i = t; i < F1 * F1; i += blockDim.x) sW1b[i] = W1b[i];
    for (int i = t; i < F1 * F2; i += blockDim.x) sW2a[i] = W2a[i];
    if (t < F1) { sb1a[t] = b1a[t]; sb1b[t] = b1b[t]; }
    __syncthreads();

    int n = blockIdx.x * blockDim.x + t;
    if (n >= N_NODES) return;

    float u[F1];
#pragma unroll
    for (int k = 0; k < F1; k++)
        u[k] = fmaxf(xw1[n * F1 + k] + agg1w[n * F1 + k] + sb1a[k], 0.0f);

    float h[F1];
#pragma unroll
    for (int j = 0; j < F1; j++) {
        float s = sb1b[j];
#pragma unroll
        for (int k = 0; k < F1; k++) s += u[k] * sW1b[k * F1 + j];
        h[j] = fmaxf(s, 0.0f);
    }
#pragma unroll
    for (int j = 0; j < F2; j++) {
        float s = 0.0f;
#pragma unroll
        for (int k = 0; k < F1; k++) s += h[k] * sW2a[k * F2 + j];
        h1w[n * F2 + j] = s;
    }
}

// ---- layer-2 tail fused with mean-pool accumulation (batch sorted) ----
__global__ void mlp2pool_k(const float* __restrict__ h1w,
                           const float* __restrict__ agg2w,
                           const float* __restrict__ b2a,
                           const float* __restrict__ W2b, const float* __restrict__ b2b,
                           const int* __restrict__ batch,
                           float* __restrict__ gsum,
                           float* __restrict__ gcnt) {
    __shared__ float sW2b[F2 * F2];
    __shared__ float sb2a[F2];
    __shared__ float sb2b[F2];
    __shared__ float ls[NGRAPH * F2];
    __shared__ float lc[NGRAPH];
    int t = threadIdx.x;
    for (int i = t; i < F2 * F2; i += blockDim.x) sW2b[i] = W2b[i];
    if (t < F2) { sb2a[t] = b2a[t]; sb2b[t] = b2b[t]; }
    for (int i = t; i < NGRAPH * F2; i += blockDim.x) ls[i] = 0.0f;
    if (t < NGRAPH) lc[t] = 0.0f;
    __syncthreads();

    int n = blockIdx.x * blockDim.x + t;
    if (n < N_NODES) {
        float u[F2];
#pragma unroll
        for (int k = 0; k < F2; k++)
            u[k] = fmaxf(h1w[n * F2 + k] + agg2w[n * F2 + k] + sb2a[k], 0.0f);

        float v[F2];
#pragma unroll
        for (int j = 0; j < F2; j++) {
            float s = sb2b[j];
#pragma unroll
            for (int k = 0; k < F2; k++) s += u[k] * sW2b[k * F2 + j];
            v[j] = fmaxf(s, 0.0f);
        }
        int g = batch[n];
#pragma unroll
        for (int j = 0; j < F2; j++) atomicAdd(&ls[g * F2 + j], v[j]);
        atomicAdd(&lc[g], 1.0f);
    }
    __syncthreads();
    for (int i = t; i < NGRAPH * F2; i += blockDim.x)
        if (ls[i] != 0.0f) atomicAdd(&gsum[i], ls[i]);
    if (t < NGRAPH && lc[t] != 0.0f) atomicAdd(&gcnt[t], lc[t]);
}

// ---------------- final: pooled -> FC -> log_softmax ----------------
__global__ void final_k(const float* __restrict__ gsum,
                        const float* __restrict__ gcnt,
                        const float* __restrict__ Wfc, const float* __restrict__ bfc,
                        float* __restrict__ out) {
    int g = threadIdx.x;
    if (g >= NGRAPH) return;
    float cnt = fmaxf(gcnt[g], 1.0f);
    float p[F2];
#pragma unroll
    for (int f = 0; f < F2; f++) p[f] = gsum[g * F2 + f] / cnt;
    float l[NCLS];
#pragma unroll
    for (int c = 0; c < NCLS; c++) {
        float s = bfc[c];
#pragma unroll
        for (int f = 0; f < F2; f++) s += p[f] * Wfc[f * NCLS + c];
        l[c] = s;
    }
    float m = -INFINITY;
#pragma unroll
    for (int c = 0; c < NCLS; c++) m = fmaxf(m, l[c]);
    float s = 0.0f;
#pragma unroll
    for (int c = 0; c < NCLS; c++) s += expf(l[c] - m);
    float lse = m + logf(s);
#pragma unroll
    for (int c = 0; c < NCLS; c++) out[g * NCLS + c] = l[c] - lse;
}

extern "C" void kernel_launch(void* const* d_in, const int* in_sizes, int n_in,
                              void* d_out, int out_size, void* d_ws, size_t ws_size,
                              hipStream_t stream) {
    const float* x    = (const float*)d_in[0];
    const int*   ei   = (const int*)d_in[1];
    const int*   batch= (const int*)d_in[2];
    const float* W1a  = (const float*)d_in[3];
    const float* b1a  = (const float*)d_in[4];
    const float* W1b  = (const float*)d_in[5];
    const float* b1b  = (const float*)d_in[6];
    const float* W2a  = (const float*)d_in[7];
    const float* b2a  = (const float*)d_in[8];
    const float* W2b  = (const float*)d_in[9];
    const float* b2b  = (const float*)d_in[10];
    const float* Wfc  = (const float*)d_in[11];
    const float* bfc  = (const float*)d_in[12];
    float* out = (float*)d_out;

    // workspace layout
    char* wsb = (char*)d_ws;
    int* deg       = (int*)wsb;                          // N_NODES
    int* row_start = deg + N_NODES;                      // N_NODES
    int* cursor    = row_start + N_NODES;                // N_NODES
    int* col       = cursor + N_NODES;                   // N_EDGES
    float* xw1     = (float*)(col + N_EDGES);            // N_NODES*16
    float* agg1w   = xw1 + (size_t)N_NODES * F1;         // N_NODES*16
    float* h1w     = agg1w + (size_t)N_NODES * F1;       // N_NODES*8
    float* agg2w   = h1w + (size_t)N_NODES * F2;         // N_NODES*8
    float* gsum    = agg2w + (size_t)N_NODES * F2;       // 64*8
    float* gcnt    = gsum + NGRAPH * F2;                 // 64

    hipMemsetAsync(deg, 0, (size_t)N_NODES * sizeof(int), stream);
    hipMemsetAsync(gsum, 0, (NGRAPH * F2 + NGRAPH) * sizeof(float), stream);

    const int EB = (N_EDGES + 255) / 256;
    // CSR build (per call — ws is re-poisoned between launches)
    hist_k<<<EB, 256, 0, stream>>>(ei, deg);
    scan_k<<<1, SCAN_THREADS, 0, stream>>>(deg, row_start, cursor);
    fill_k<<<EB, 256, 0, stream>>>(ei, cursor, col);

    xform1_k<<<(N_NODES + 255) / 256, 256, 0, stream>>>(x, W1a, xw1);
    gather16_k<<<((N_NODES * F1) + 255) / 256, 256, 0, stream>>>(xw1, row_start, deg, col, agg1w);
    mlp1b_k<<<(N_NODES + 255) / 256, 256, 0, stream>>>(xw1, agg1w, b1a, W1b, b1b, W2a, h1w);
    gather8_k<<<((N_NODES * F2) + 255) / 256, 256, 0, stream>>>(h1w, row_start, deg, col, agg2w);
    mlp2pool_k<<<(N_NODES + 255) / 256, 256, 0, stream>>>(h1w, agg2w, b2a, W2b, b2b,
                                                          batch, gsum, gcnt);
    final_k<<<1, 64, 0, stream>>>(gsum, gcnt, Wfc, bfc, out);
}

// Round 4
// 388.632 us; speedup vs baseline: 1.5600x; 1.5600x over previous
//
#include <hip/hip_runtime.h>
#include <hip/hip_bf16.h>
#include <math.h>

#define N_NODES 100000
#define N_EDGES 1600000
#define F0 32
#define F1 16
#define F2 8
#define NCLS 6
#define NGRAPH 64
#define SB 1024                       // scan block size
#define NB_SCAN ((N_NODES + SB - 1) / SB)   // 98

// ---------------- CSR build: histogram of dst degrees ----------------
__global__ void hist_k(const int* __restrict__ ei, int* __restrict__ deg) {
    int e = blockIdx.x * blockDim.x + threadIdx.x;
    if (e >= N_EDGES) return;
    atomicAdd(&deg[ei[N_EDGES + e]], 1);
}

// ---- scan phase 1: per-block exclusive scan + block sums ----
__global__ void scan1_k(const int* __restrict__ deg,
                        int* __restrict__ excl,
                        int* __restrict__ bsum) {
    __shared__ int s[SB];
    int t = threadIdx.x;
    int i = blockIdx.x * SB + t;
    int v = (i < N_NODES) ? deg[i] : 0;
    s[t] = v;
    __syncthreads();
    for (int off = 1; off < SB; off <<= 1) {
        int u = (t >= off) ? s[t - off] : 0;
        __syncthreads();
        s[t] += u;
        __syncthreads();
    }
    if (i < N_NODES) excl[i] = s[t] - v;
    if (t == SB - 1) bsum[blockIdx.x] = s[t];
}

// ---- scan phase 2: exclusive scan of the 98 block sums (one tiny block) ----
__global__ void scan2_k(int* __restrict__ bsum) {
    __shared__ int s[128];
    int t = threadIdx.x;
    int v = (t < NB_SCAN) ? bsum[t] : 0;
    s[t] = v;
    __syncthreads();
    for (int off = 1; off < 128; off <<= 1) {
        int u = (t >= off) ? s[t - off] : 0;
        __syncthreads();
        s[t] += u;
        __syncthreads();
    }
    if (t < NB_SCAN) bsum[t] = s[t] - v;   // exclusive
}

// ---- scan phase 3: add block offsets, emit row_start and cursor ----
__global__ void scan3_k(int* __restrict__ row_start,
                        const int* __restrict__ bsum,
                        int* __restrict__ cursor) {
    int i = blockIdx.x * blockDim.x + threadIdx.x;
    if (i >= N_NODES) return;
    int r = row_start[i] + bsum[i >> 10];
    row_start[i] = r;
    cursor[i] = r;
}

// ---- fill: col[pos] = src, pos = fetch-add on cursor[dst] ----
__global__ void fill_k(const int* __restrict__ ei,
                       int* __restrict__ cursor,
                       int* __restrict__ col) {
    int e = blockIdx.x * blockDim.x + threadIdx.x;
    if (e >= N_EDGES) return;
    int src = ei[e];
    int dst = ei[N_EDGES + e];
    int pos = atomicAdd(&cursor[dst], 1);
    col[pos] = src;
}

// ---- xform1: xw1 = x @ W1a (32 -> 16, projected before aggregation) ----
__global__ void xform1_k(const float* __restrict__ x,
                         const float* __restrict__ W1a,
                         float* __restrict__ xw1) {
    __shared__ float sW[F0 * F1];
    int t = threadIdx.x;
    for (int i = t; i < F0 * F1; i += blockDim.x) sW[i] = W1a[i];
    __syncthreads();
    int n = blockIdx.x * blockDim.x + t;
    if (n >= N_NODES) return;
    float xi[F0];
#pragma unroll
    for (int k = 0; k < F0; k++) xi[k] = x[n * F0 + k];
#pragma unroll
    for (int j = 0; j < F1; j++) {
        float s = 0.0f;
#pragma unroll
        for (int k = 0; k < F0; k++) s += xi[k] * sW[k * F1 + j];
        xw1[n * F1 + j] = s;
    }
}

// ---- gather 16 feats: agg[n] = sum over in-edges of v[col[j]] ----
__global__ void gather16_k(const float* __restrict__ v,
                           const int* __restrict__ row_start,
                           const int* __restrict__ deg,
                           const int* __restrict__ col,
                           float* __restrict__ agg) {
    int tid = blockIdx.x * blockDim.x + threadIdx.x;
    int n = tid >> 4;
    int f = tid & 15;
    if (n >= N_NODES) return;
    int lo = row_start[n];
    int d = deg[n];
    float s = 0.0f;
    for (int j = 0; j < d; j++)
        s += v[col[lo + j] * F1 + f];
    agg[n * F1 + f] = s;
}

// ---- gather 8 feats ----
__global__ void gather8_k(const float* __restrict__ v,
                          const int* __restrict__ row_start,
                          const int* __restrict__ deg,
                          const int* __restrict__ col,
                          float* __restrict__ agg) {
    int tid = blockIdx.x * blockDim.x + threadIdx.x;
    int n = tid >> 3;
    int f = tid & 7;
    if (n >= N_NODES) return;
    int lo = row_start[n];
    int d = deg[n];
    float s = 0.0f;
    for (int j = 0; j < d; j++)
        s += v[col[lo + j] * F2 + f];
    agg[n * F2 + f] = s;
}

// ---- mlp1b: u = relu(xw1 + agg1w + b1a); h1 = relu(u@W1b + b1b);
//      h1w = h1 @ W2a (projected for the next gather) ----
__global__ void mlp1b_k(const float* __restrict__ xw1,
                        const float* __restrict__ agg1w,
                        const float* __restrict__ b1a,
                        const float* __restrict__ W1b, const float* __restrict__ b1b,
                        const float* __restrict__ W2a,
                        float* __restrict__ h1w) {
    __shared__ float sW1b[F1 * F1];
    __shared__ float sW2a[F1 * F2];
    __shared__ float sb1a[F1];
    __shared__ float sb1b[F1];
    int t = threadIdx.x;
    for (int i = t; i < F1 * F1; i += blockDim.x) sW1b[i] = W1b[i];
    for (int i = t; i < F1 * F2; i += blockDim.x) sW2a[i] = W2a[i];
    if (t < F1) { sb1a[t] = b1a[t]; sb1b[t] = b1b[t]; }
    __syncthreads();

    int n = blockIdx.x * blockDim.x + t;
    if (n >= N_NODES) return;

    float u[F1];
#pragma unroll
    for (int k = 0; k < F1; k++)
        u[k] = fmaxf(xw1[n * F1 + k] + agg1w[n * F1 + k] + sb1a[k], 0.0f);

    float h[F1];
#pragma unroll
    for (int j = 0; j < F1; j++) {
        float s = sb1b[j];
#pragma unroll
        for (int k = 0; k < F1; k++) s += u[k] * sW1b[k * F1 + j];
        h[j] = fmaxf(s, 0.0f);
    }
#pragma unroll
    for (int j = 0; j < F2; j++) {
        float s = 0.0f;
#pragma unroll
        for (int k = 0; k < F1; k++) s += h[k] * sW2a[k * F2 + j];
        h1w[n * F2 + j] = s;
    }
}

// ---- layer-2 tail fused with mean-pool accumulation (batch sorted) ----
__global__ void mlp2pool_k(const float* __restrict__ h1w,
                           const float* __restrict__ agg2w,
                           const float* __restrict__ b2a,
                           const float* __restrict__ W2b, const float* __restrict__ b2b,
                           const int* __restrict__ batch,
                           float* __restrict__ gsum,
                           float* __restrict__ gcnt) {
    __shared__ float sW2b[F2 * F2];
    __shared__ float sb2a[F2];
    __shared__ float sb2b[F2];
    __shared__ float ls[NGRAPH * F2];
    __shared__ float lc[NGRAPH];
    int t = threadIdx.x;
    for (int i = t; i < F2 * F2; i += blockDim.x) sW2b[i] = W2b[i];
    if (t < F2) { sb2a[t] = b2a[t]; sb2b[t] = b2b[t]; }
    for (int i = t; i < NGRAPH * F2; i += blockDim.x) ls[i] = 0.0f;
    if (t < NGRAPH) lc[t] = 0.0f;
    __syncthreads();

    int n = blockIdx.x * blockDim.x + t;
    if (n < N_NODES) {
        float u[F2];
#pragma unroll
        for (int k = 0; k < F2; k++)
            u[k] = fmaxf(h1w[n * F2 + k] + agg2w[n * F2 + k] + sb2a[k], 0.0f);

        float v[F2];
#pragma unroll
        for (int j = 0; j < F2; j++) {
            float s = sb2b[j];
#pragma unroll
            for (int k = 0; k < F2; k++) s += u[k] * sW2b[k * F2 + j];
            v[j] = fmaxf(s, 0.0f);
        }
        int g = batch[n];
#pragma unroll
        for (int j = 0; j < F2; j++) atomicAdd(&ls[g * F2 + j], v[j]);
        atomicAdd(&lc[g], 1.0f);
    }
    __syncthreads();
    for (int i = t; i < NGRAPH * F2; i += blockDim.x)
        if (ls[i] != 0.0f) atomicAdd(&gsum[i], ls[i]);
    if (t < NGRAPH && lc[t] != 0.0f) atomicAdd(&gcnt[t], lc[t]);
}

// ---------------- final: pooled -> FC -> log_softmax ----------------
__global__ void final_k(const float* __restrict__ gsum,
                        const float* __restrict__ gcnt,
                        const float* __restrict__ Wfc, const float* __restrict__ bfc,
                        float* __restrict__ out) {
    int g = threadIdx.x;
    if (g >= NGRAPH) return;
    float cnt = fmaxf(gcnt[g], 1.0f);
    float p[F2];
#pragma unroll
    for (int f = 0; f < F2; f++) p[f] = gsum[g * F2 + f] / cnt;
    float l[NCLS];
#pragma unroll
    for (int c = 0; c < NCLS; c++) {
        float s = bfc[c];
#pragma unroll
        for (int f = 0; f < F2; f++) s += p[f] * Wfc[f * NCLS + c];
        l[c] = s;
    }
    float m = -INFINITY;
#pragma unroll
    for (int c = 0; c < NCLS; c++) m = fmaxf(m, l[c]);
    float s = 0.0f;
#pragma unroll
    for (int c = 0; c < NCLS; c++) s += expf(l[c] - m);
    float lse = m + logf(s);
#pragma unroll
    for (int c = 0; c < NCLS; c++) out[g * NCLS + c] = l[c] - lse;
}

extern "C" void kernel_launch(void* const* d_in, const int* in_sizes, int n_in,
                              void* d_out, int out_size, void* d_ws, size_t ws_size,
                              hipStream_t stream) {
    const float* x    = (const float*)d_in[0];
    const int*   ei   = (const int*)d_in[1];
    const int*   batch= (const int*)d_in[2];
    const float* W1a  = (const float*)d_in[3];
    const float* b1a  = (const float*)d_in[4];
    const float* W1b  = (const float*)d_in[5];
    const float* b1b  = (const float*)d_in[6];
    const float* W2a  = (const float*)d_in[7];
    const float* b2a  = (const float*)d_in[8];
    const float* W2b  = (const float*)d_in[9];
    const float* b2b  = (const float*)d_in[10];
    const float* Wfc  = (const float*)d_in[11];
    const float* bfc  = (const float*)d_in[12];
    float* out = (float*)d_out;

    // workspace layout
    char* wsb = (char*)d_ws;
    int* deg       = (int*)wsb;                          // N_NODES
    int* row_start = deg + N_NODES;                      // N_NODES
    int* cursor    = row_start + N_NODES;                // N_NODES
    int* bsum      = cursor + N_NODES;                   // NB_SCAN (98)
    int* col       = bsum + 128;                         // N_EDGES
    float* xw1     = (float*)(col + N_EDGES);            // N_NODES*16
    float* agg1w   = xw1 + (size_t)N_NODES * F1;         // N_NODES*16
    float* h1w     = agg1w + (size_t)N_NODES * F1;       // N_NODES*8
    float* agg2w   = h1w + (size_t)N_NODES * F2;         // N_NODES*8
    float* gsum    = agg2w + (size_t)N_NODES * F2;       // 64*8
    float* gcnt    = gsum + NGRAPH * F2;                 // 64

    hipMemsetAsync(deg, 0, (size_t)N_NODES * sizeof(int), stream);
    hipMemsetAsync(gsum, 0, (NGRAPH * F2 + NGRAPH) * sizeof(float), stream);

    const int EB = (N_EDGES + 255) / 256;
    // CSR build (per call — ws is re-poisoned between launches)
    hist_k<<<EB, 256, 0, stream>>>(ei, deg);
    scan1_k<<<NB_SCAN, SB, 0, stream>>>(deg, row_start, bsum);
    scan2_k<<<1, 128, 0, stream>>>(bsum);
    scan3_k<<<(N_NODES + 255) / 256, 256, 0, stream>>>(row_start, bsum, cursor);
    fill_k<<<EB, 256, 0, stream>>>(ei, cursor, col);

    xform1_k<<<(N_NODES + 255) / 256, 256, 0, stream>>>(x, W1a, xw1);
    gather16_k<<<((N_NODES * F1) + 255) / 256, 256, 0, stream>>>(xw1, row_start, deg, col, agg1w);
    mlp1b_k<<<(N_NODES + 255) / 256, 256, 0, stream>>>(xw1, agg1w, b1a, W1b, b1b, W2a, h1w);
    gather8_k<<<((N_NODES * F2) + 255) / 256, 256, 0, stream>>>(h1w, row_start, deg, col, agg2w);
    mlp2pool_k<<<(N_NODES + 255) / 256, 256, 0, stream>>>(h1w, agg2w, b2a, W2b, b2b,
                                                          batch, gsum, gcnt);
    final_k<<<1, 64, 0, stream>>>(gsum, gcnt, Wfc, bfc, out);
}